// Round 7
// baseline (52.296 us; speedup 1.0000x reference)
//
#include <hip/hip_runtime.h>

// GreedyThresh decode: B=4096 rows, V=128 sequential steps, U1=129 cols.
// r7: TWO independent batch rows per wave (A,B) -> two interleaved dependent
// chains per wave; row B's ops fill row A's DPP/readlane hazard slots.
// Builtin update_dpp (compiler handles hazards; no s_nop issue-burn).
//
// Key packing (verified r2/r4): candidates in [0.5,1.0) => biased exp 126
// (LSB 0), so (bits<<8) == (mant<<8) exactly; key = (bits<<8) | (255-col).
// Max key == max value then lowest column (jnp.argmax tie-break). Keys < 2^31.
// keep-update via (masked_key == winner_key): unique per column, and the
// winner compare value is forced to ~0 (impossible key) on fallback steps.
// size accumulated exactly as 0.5*nsel + msum*2^-24 (msum < 2^30).

#define NB 4096
#define NV 128
#define NU1 129
#define R 2     // rows per wave
#define WPB 4   // waves per block
#define PD 8    // prefetch depth (rows in flight per wave per batch-row)

__device__ __forceinline__ unsigned mkkey(float v, unsigned inv) {
    unsigned k = (__float_as_uint(v) << 8) | inv;
    return v >= 0.5f ? k : 0u;
}

#define DPPSTAGE(v, ctl)                                                       \
    { int _t = __builtin_amdgcn_update_dpp(0, v, ctl, 0xf, 0xf, true);         \
      v = v > _t ? v : _t; }

__global__ __launch_bounds__(256)
void greedy_thresh_kernel(const float* __restrict__ w, float* __restrict__ out) {
    const int wave = blockIdx.x * WPB + (threadIdx.x >> 6);
    const int lane = threadIdx.x & 63;

    const int rowA = wave * R;                    // batch rows rowA, rowA+1
    const float* __restrict__ wbA = w + (size_t)rowA * (NV * NU1);
    const float* __restrict__ wbB = wbA + (NV * NU1);
    float* __restrict__ out_neg = out;            // [NB]  (-size)
    float* __restrict__ out_sel = out + NB;       // [NB*NV] (sel as float)

    const int c0 = 1 + lane;            // 1..64
    const int c1 = 65 + lane;           // 65..128
    const unsigned inv0 = 255 - c0;
    const unsigned inv1 = 255 - c1;

    unsigned kpA0 = ~0u, kpA1 = ~0u, kpB0 = ~0u, kpB1 = ~0u;  // keep masks
    unsigned msumA = 0u, nselA = 0u, msumB = 0u, nselB = 0u;  // size accum (SGPR)
    int sA0 = 0, sA1 = 0, sB0 = 0, sB1 = 0;  // this lane's sels (iters 2l,2l+1)

    float pA0[PD], pA1[PD], pB0[PD], pB1[PD];
    #pragma unroll
    for (int d = 0; d < PD; ++d) {
        pA0[d] = wbA[d * NU1 + c0];
        pA1[d] = wbA[d * NU1 + c1];
        pB0[d] = wbB[d * NU1 + c0];
        pB1[d] = wbB[d * NU1 + c1];
    }
    unsigned krA0 = mkkey(pA0[0], inv0), krA1 = mkkey(pA1[0], inv1);
    unsigned krB0 = mkkey(pB0[0], inv0), krB1 = mkkey(pB1[0], inv1);

#define BODY(iexpr, dd, PREF, BLD)                                             \
    {                                                                          \
        const int i = (iexpr);                                                 \
        const unsigned aA0 = krA0 & kpA0, aA1 = krA1 & kpA1;                   \
        const unsigned aB0 = krB0 & kpB0, aB1 = krB1 & kpB1;                   \
        int vA = (int)(aA0 > aA1 ? aA0 : aA1);                                 \
        int vB = (int)(aB0 > aB1 ? aB0 : aB1);                                 \
        if (PREF) {                                                            \
            const float* nA = wbA + (size_t)(i + PD) * NU1;                    \
            const float* nB = wbB + (size_t)(i + PD) * NU1;                    \
            pA0[dd] = nA[c0]; pA1[dd] = nA[c1];                                \
            pB0[dd] = nB[c0]; pB1[dd] = nB[c1];                                \
        }                                                                      \
        if (BLD) {                                                             \
            krA0 = mkkey(pA0[(dd + 1) & (PD - 1)], inv0);                      \
            krA1 = mkkey(pA1[(dd + 1) & (PD - 1)], inv1);                      \
            krB0 = mkkey(pB0[(dd + 1) & (PD - 1)], inv0);                      \
            krB1 = mkkey(pB1[(dd + 1) & (PD - 1)], inv1);                      \
        }                                                                      \
        DPPSTAGE(vA, 0x111) DPPSTAGE(vB, 0x111)  /* row_shr:1  */             \
        DPPSTAGE(vA, 0x112) DPPSTAGE(vB, 0x112)  /* row_shr:2  */             \
        DPPSTAGE(vA, 0x114) DPPSTAGE(vB, 0x114)  /* row_shr:4  */             \
        DPPSTAGE(vA, 0x118) DPPSTAGE(vB, 0x118)  /* row_shr:8  */             \
        DPPSTAGE(vA, 0x142) DPPSTAGE(vB, 0x142)  /* row_bcast:15 */           \
        DPPSTAGE(vA, 0x143) DPPSTAGE(vB, 0x143)  /* row_bcast:31 */           \
        const unsigned kkA = (unsigned)__builtin_amdgcn_readlane(vA, 63);      \
        const unsigned kkB = (unsigned)__builtin_amdgcn_readlane(vB, 63);      \
        const unsigned cvA = kkA ? kkA : ~0u;   /* impossible key on fallback */ \
        const unsigned cvB = kkB ? kkB : ~0u;                                  \
        kpA0 = (aA0 == cvA) ? 0u : kpA0;  kpA1 = (aA1 == cvA) ? 0u : kpA1;     \
        kpB0 = (aB0 == cvB) ? 0u : kpB0;  kpB1 = (aB1 == cvB) ? 0u : kpB1;     \
        msumA += (kkA >> 8);  nselA += (kkA != 0u);                            \
        msumB += (kkB >> 8);  nselB += (kkB != 0u);                            \
        const int selA = kkA ? (255 - (int)(kkA & 0xFFu)) : 0;                 \
        const int selB = kkB ? (255 - (int)(kkB & 0xFFu)) : 0;                 \
        if ((i >> 1) == lane) {                                                \
            if (i & 1) { sA1 = selA; sB1 = selB; }                             \
            else       { sA0 = selA; sB0 = selB; }                             \
        }                                                                      \
    }

    // main: 15 blocks with prefetch; tail block without
    for (int ib = 0; ib < NV - PD; ib += PD) {
        #pragma unroll
        for (int d = 0; d < PD; ++d)
            BODY(ib + d, d, true, true)
    }
    #pragma unroll
    for (int d = 0; d < PD; ++d)
        BODY(NV - PD + d, d, false, (d < PD - 1))

#undef BODY

    // coalesced epilogue: lane j writes sels for iterations 2j, 2j+1
    *reinterpret_cast<float2*>(&out_sel[(size_t)rowA * NV + 2 * lane]) =
        make_float2((float)sA0, (float)sA1);
    *reinterpret_cast<float2*>(&out_sel[(size_t)(rowA + 1) * NV + 2 * lane]) =
        make_float2((float)sB0, (float)sB1);
    if (lane == 0) {
        out_neg[rowA]     = -(0.5f * (float)nselA + (float)msumA * 0x1p-24f);
        out_neg[rowA + 1] = -(0.5f * (float)nselB + (float)msumB * 0x1p-24f);
    }
}

extern "C" void kernel_launch(void* const* d_in, const int* in_sizes, int n_in,
                              void* d_out, int out_size, void* d_ws, size_t ws_size,
                              hipStream_t stream) {
    const float* w = (const float*)d_in[0];
    float* out = (float*)d_out;
    const int blocks = NB / (R * WPB);  // 512
    greedy_thresh_kernel<<<blocks, 64 * WPB, 0, stream>>>(w, out);
}

// Round 9
// 50.789 us; speedup vs baseline: 1.0297x; 1.0297x over previous
//
#include <hip/hip_runtime.h>

// GreedyThresh decode: B=4096 rows, V=128 sequential steps, U1=129 cols.
// One wave per batch row; lane l owns cols 1+l and 65+l.
// Key packing (verified r2/r4/r6): candidates in [0.5,1.0) => biased exp 126
// (LSB 0), so (bits<<8) == (mant<<8); key = (bits<<8) | (255-col). Max key ==
// max value then lowest column (jnp.argmax tie-break). Keys < 2^31.
//
// r8: R=1 (r7's R=2 regressed: halved TLP cost 9%), PD=16 (deeper latency
// cover; 32 loads in flight/wave), sequential fp32 size accumulation
// (bit-identical to reference's per-step adds -> absmax 0; r7's exact-int
// sum drifted ~1e-4 and crossed a bf16-compare boundary -> 0.5),
// keep-update via key-compare (r7; equivalent, shorter chain).

#define NB 4096
#define NV 128
#define NU1 129
#define WPB 4
#define PD 16   // prefetch depth (rows in flight per wave), power of 2

__device__ __forceinline__ unsigned mkkey(float v, unsigned inv) {
    unsigned k = (__float_as_uint(v) << 8) | inv;
    return v >= 0.5f ? k : 0u;
}

#define DPPSTAGE(v, ctl)                                                       \
    { int _t = __builtin_amdgcn_update_dpp(0, v, ctl, 0xf, 0xf, true);         \
      v = v > _t ? v : _t; }

__global__ __launch_bounds__(256)
void greedy_thresh_kernel(const float* __restrict__ w, float* __restrict__ out) {
    const int wave = blockIdx.x * WPB + (threadIdx.x >> 6);
    const int lane = threadIdx.x & 63;

    const float* __restrict__ wb = w + (size_t)wave * (NV * NU1);
    float* __restrict__ out_neg = out;            // [NB]  (-size)
    float* __restrict__ out_sel = out + NB;       // [NB*NV] (sel as float)

    const int c0 = 1 + lane;            // 1..64
    const int c1 = 65 + lane;           // 65..128
    const unsigned inv0 = 255 - c0;     // 191..254
    const unsigned inv1 = 255 - c1;     // 127..190  (disjoint, all unique)

    unsigned kp0 = ~0u, kp1 = ~0u;      // keep masks (0 once column matched)
    float size = 0.0f;
    int s0 = 0, s1 = 0;                 // this lane's sels (iters 2l, 2l+1)

    float p0[PD], p1[PD];               // prefetch ring, PD rows in flight
    #pragma unroll
    for (int d = 0; d < PD; ++d) {
        p0[d] = wb[d * NU1 + c0];
        p1[d] = wb[d * NU1 + c1];
    }
    unsigned kr0 = mkkey(p0[0], inv0);
    unsigned kr1 = mkkey(p1[0], inv1);

#define BODY(iexpr, dd, PREF, BLD)                                             \
    {                                                                          \
        const int i = (iexpr);                                                 \
        const unsigned a0 = kr0 & kp0;                                         \
        const unsigned a1 = kr1 & kp1;                                         \
        int v = (int)(a0 > a1 ? a0 : a1);                                      \
        if (PREF) {                                                            \
            const float* nrow = wb + (size_t)(i + PD) * NU1;                   \
            p0[dd] = nrow[c0];                                                 \
            p1[dd] = nrow[c1];                                                 \
        }                                                                      \
        if (BLD) {                                                             \
            kr0 = mkkey(p0[(dd + 1) & (PD - 1)], inv0);                        \
            kr1 = mkkey(p1[(dd + 1) & (PD - 1)], inv1);                        \
        }                                                                      \
        DPPSTAGE(v, 0x111)  /* row_shr:1  */                                   \
        DPPSTAGE(v, 0x112)  /* row_shr:2  */                                   \
        DPPSTAGE(v, 0x114)  /* row_shr:4  */                                   \
        DPPSTAGE(v, 0x118)  /* row_shr:8  */                                   \
        DPPSTAGE(v, 0x142)  /* row_bcast:15 */                                 \
        DPPSTAGE(v, 0x143)  /* row_bcast:31 */                                 \
        const unsigned kk = (unsigned)__builtin_amdgcn_readlane(v, 63);        \
        const unsigned cv = kk ? kk : ~0u;  /* impossible key on fallback */   \
        kp0 = (a0 == cv) ? 0u : kp0;                                           \
        kp1 = (a1 == cv) ? 0u : kp1;                                           \
        /* sequential fp32 add, same order as reference -> bit-identical */    \
        size += __uint_as_float(kk ? (0x3F000000u | (kk >> 8)) : 0u);          \
        const int sel = kk ? (255 - (int)(kk & 0xFFu)) : 0;                    \
        if ((i >> 1) == lane) { if (i & 1) s1 = sel; else s0 = sel; }          \
    }

    // main: blocks with prefetch; tail block without
    for (int ib = 0; ib < NV - PD; ib += PD) {
        #pragma unroll
        for (int d = 0; d < PD; ++d)
            BODY(ib + d, d, true, true)
    }
    #pragma unroll
    for (int d = 0; d < PD; ++d)
        BODY(NV - PD + d, d, false, (d < PD - 1))

#undef BODY

    // coalesced epilogue: lane j writes sels for iterations 2j, 2j+1
    *reinterpret_cast<float2*>(&out_sel[(size_t)wave * NV + 2 * lane]) =
        make_float2((float)s0, (float)s1);
    if (lane == 0) out_neg[wave] = -size;
}

extern "C" void kernel_launch(void* const* d_in, const int* in_sizes, int n_in,
                              void* d_out, int out_size, void* d_ws, size_t ws_size,
                              hipStream_t stream) {
    const float* w = (const float*)d_in[0];
    float* out = (float*)d_out;
    const int blocks = NB / WPB;  // 1024
    greedy_thresh_kernel<<<blocks, 64 * WPB, 0, stream>>>(w, out);
}

// Round 10
// 48.694 us; speedup vs baseline: 1.0740x; 1.0430x over previous
//
#include <hip/hip_runtime.h>

// GreedyThresh decode: B=4096 rows, V=128 sequential steps, U1=129 cols.
// One wave per batch row; lane l owns cols 1+l and 65+l.
// Key packing (verified r2-r9): candidates in [0.5,1.0) => biased exp 126
// (LSB 0), so (bits<<8) == (mant<<8); key = (bits<<8) | (255-col). Max key ==
// max value then lowest column (jnp.argmax tie-break). Keys < 2^31.
//
// r10: revert PD to 8 (r9's PD=16 regressed 47.8->50.8: depth beyond 8 only
// adds live regs/issue work). Keep r8 body: key-compare keep-update,
// sequential fp32 size accumulation (bit-identical to ref; absmax 0).
// New: 5 DPP stages + dual readlane(31,63) + scalar max finish — after 5
// stages lane31 = max(lanes 0..31), lane63 = max(lanes 32..63); the final
// combine runs on the scalar pipe, off the VALU chain.

#define NB 4096
#define NV 128
#define NU1 129
#define WPB 4
#define PD 8    // prefetch depth (rows in flight per wave), power of 2

__device__ __forceinline__ unsigned mkkey(float v, unsigned inv) {
    unsigned k = (__float_as_uint(v) << 8) | inv;
    return v >= 0.5f ? k : 0u;
}

#define DPPSTAGE(v, ctl)                                                       \
    { int _t = __builtin_amdgcn_update_dpp(0, v, ctl, 0xf, 0xf, true);         \
      v = v > _t ? v : _t; }

__global__ __launch_bounds__(256)
void greedy_thresh_kernel(const float* __restrict__ w, float* __restrict__ out) {
    const int wave = blockIdx.x * WPB + (threadIdx.x >> 6);
    const int lane = threadIdx.x & 63;

    const float* __restrict__ wb = w + (size_t)wave * (NV * NU1);
    float* __restrict__ out_neg = out;            // [NB]  (-size)
    float* __restrict__ out_sel = out + NB;       // [NB*NV] (sel as float)

    const int c0 = 1 + lane;            // 1..64
    const int c1 = 65 + lane;           // 65..128
    const unsigned inv0 = 255 - c0;     // 191..254
    const unsigned inv1 = 255 - c1;     // 127..190  (disjoint, all unique)

    unsigned kp0 = ~0u, kp1 = ~0u;      // keep masks (0 once column matched)
    float size = 0.0f;
    int s0 = 0, s1 = 0;                 // this lane's sels (iters 2l, 2l+1)

    float p0[PD], p1[PD];               // prefetch ring, PD rows in flight
    #pragma unroll
    for (int d = 0; d < PD; ++d) {
        p0[d] = wb[d * NU1 + c0];
        p1[d] = wb[d * NU1 + c1];
    }
    unsigned kr0 = mkkey(p0[0], inv0);
    unsigned kr1 = mkkey(p1[0], inv1);

#define BODY(iexpr, dd, PREF, BLD)                                             \
    {                                                                          \
        const int i = (iexpr);                                                 \
        const unsigned a0 = kr0 & kp0;                                         \
        const unsigned a1 = kr1 & kp1;                                         \
        int v = (int)(a0 > a1 ? a0 : a1);                                      \
        if (PREF) {                                                            \
            const float* nrow = wb + (size_t)(i + PD) * NU1;                   \
            p0[dd] = nrow[c0];                                                 \
            p1[dd] = nrow[c1];                                                 \
        }                                                                      \
        if (BLD) {                                                             \
            kr0 = mkkey(p0[(dd + 1) & (PD - 1)], inv0);                        \
            kr1 = mkkey(p1[(dd + 1) & (PD - 1)], inv1);                        \
        }                                                                      \
        DPPSTAGE(v, 0x111)  /* row_shr:1  */                                   \
        DPPSTAGE(v, 0x112)  /* row_shr:2  */                                   \
        DPPSTAGE(v, 0x114)  /* row_shr:4  */                                   \
        DPPSTAGE(v, 0x118)  /* row_shr:8  */                                   \
        DPPSTAGE(v, 0x142)  /* row_bcast:15 -> lane31=max(0..31), lane63=max(32..63) */ \
        const unsigned kh = (unsigned)__builtin_amdgcn_readlane(v, 31);        \
        const unsigned kl = (unsigned)__builtin_amdgcn_readlane(v, 63);        \
        const unsigned kk = kh > kl ? kh : kl;   /* scalar-pipe max */         \
        const unsigned cv = kk ? kk : ~0u;  /* impossible key on fallback */   \
        kp0 = (a0 == cv) ? 0u : kp0;                                           \
        kp1 = (a1 == cv) ? 0u : kp1;                                           \
        /* sequential fp32 add, same order as reference -> bit-identical */    \
        size += __uint_as_float(kk ? (0x3F000000u | (kk >> 8)) : 0u);          \
        const int sel = kk ? (255 - (int)(kk & 0xFFu)) : 0;                    \
        if ((i >> 1) == lane) { if (i & 1) s1 = sel; else s0 = sel; }          \
    }

    // main: blocks with prefetch; tail block without
    for (int ib = 0; ib < NV - PD; ib += PD) {
        #pragma unroll
        for (int d = 0; d < PD; ++d)
            BODY(ib + d, d, true, true)
    }
    #pragma unroll
    for (int d = 0; d < PD; ++d)
        BODY(NV - PD + d, d, false, (d < PD - 1))

#undef BODY

    // coalesced epilogue: lane j writes sels for iterations 2j, 2j+1
    *reinterpret_cast<float2*>(&out_sel[(size_t)wave * NV + 2 * lane]) =
        make_float2((float)s0, (float)s1);
    if (lane == 0) out_neg[wave] = -size;
}

extern "C" void kernel_launch(void* const* d_in, const int* in_sizes, int n_in,
                              void* d_out, int out_size, void* d_ws, size_t ws_size,
                              hipStream_t stream) {
    const float* w = (const float*)d_in[0];
    float* out = (float*)d_out;
    const int blocks = NB / WPB;  // 1024
    greedy_thresh_kernel<<<blocks, 64 * WPB, 0, stream>>>(w, out);
}